// Round 7
// baseline (276.967 us; speedup 1.0000x reference)
//
#include <hip/hip_runtime.h>
#include <hip/hip_bf16.h>

#define B_ 32
#define S_ 64
#define H_ 300
#define H2_ 600
#define L_ 20
#define ROW_ 160                    // 8 pieces * 20
#define OUTQ_OFF ((size_t)B_ * S_ * ROW_)
#define NEG_INF -3.402823466e38f

// ---------------- K0: w^2 table [widx][l][h]
__global__ void k_w2(const float* __restrict__ Wf, float* __restrict__ w2) {
  int i = blockIdx.x * 256 + threadIdx.x;
  if (i < 8 * L_ * H_) { float v = Wf[i]; w2[i] = v * v; }
}

// ---------------- K1: plain cosine matrix per (b,dir) + fp64 row/col sums.
__global__ __launch_bounds__(256) void k_cos(const float* __restrict__ P,
                                             const float* __restrict__ Q,
                                             float* __restrict__ cosM,
                                             float* __restrict__ sum_p,
                                             float* __restrict__ sum_q) {
  int bd = blockIdx.x;
  int b = bd >> 1, dir = bd & 1;
  __shared__ float xp[S_][101];
  __shared__ float xq[S_][101];
  __shared__ float pn[S_], qn[S_];
  __shared__ float cosL[S_][S_ + 1];
  int t = threadIdx.x;
  int w = t >> 6, lane = t & 63;
  float dot[16];
#pragma unroll
  for (int k = 0; k < 16; ++k) dot[k] = 0.f;
  float np2 = 0.f, nq2 = 0.f;
  const float* Pb = P + (size_t)b * S_ * H2_ + dir * H_;
  const float* Qb = Q + (size_t)b * S_ * H2_ + dir * H_;
  for (int c0 = 0; c0 < H_; c0 += 100) {
    __syncthreads();
    for (int idx = t; idx < S_ * 100; idx += 256) {
      int s = idx / 100, hh = idx - s * 100;
      xp[s][hh] = Pb[(size_t)s * H2_ + c0 + hh];
      xq[s][hh] = Qb[(size_t)s * H2_ + c0 + hh];
    }
    __syncthreads();
    for (int hh = 0; hh < 100; ++hh) {
      float qv = xq[lane][hh];
#pragma unroll
      for (int k = 0; k < 16; ++k) dot[k] = fmaf(xp[w + 4 * k][hh], qv, dot[k]);
    }
    if (t < S_) {
      for (int hh = 0; hh < 100; ++hh) { float v = xp[t][hh]; np2 = fmaf(v, v, np2); }
    } else if (t < 2 * S_) {
      int s2 = t - S_;
      for (int hh = 0; hh < 100; ++hh) { float v = xq[s2][hh]; nq2 = fmaf(v, v, nq2); }
    }
  }
  if (t < S_) pn[t] = sqrtf(np2);
  else if (t < 2 * S_) qn[t - S_] = sqrtf(nq2);
  __syncthreads();
  float* cm = cosM + (size_t)bd * S_ * S_;
#pragma unroll
  for (int k = 0; k < 16; ++k) {
    int p = w + 4 * k;
    float c = dot[k] / (pn[p] * qn[lane]);
    cosL[p][lane] = c;
    cm[p * S_ + lane] = c;
  }
  __syncthreads();
  if (t < S_) {            // sum over p at q=t  (cos.sum(axis=1))
    double acc = 0.0;
    for (int p = 0; p < S_; ++p) acc += (double)cosL[p][t];
    sum_p[bd * S_ + t] = (float)acc;
  } else if (t < 2 * S_) { // sum over q at p=t-64  (cos.sum(axis=2))
    int r = t - S_;
    double acc = 0.0;
    for (int q = 0; q < S_; ++q) acc += (double)cosL[r][q];
    sum_q[bd * S_ + r] = (float)acc;
  }
}

// ---------------- K2: maxpool matching. R7: 2 l per block (640 blocks) ->
// 10 ds_read per 32 FMA; conflict-free swizzled tiles p=pi+16i, q=qi+16j.
__global__ __launch_bounds__(256) void k_maxpool(const float* __restrict__ P,
                                                 const float* __restrict__ Q,
                                                 const float* __restrict__ w2,
                                                 float* __restrict__ out) {
  int lg = blockIdx.x % 10;          // l-group of 2
  int bd = blockIdx.x / 10;
  int b = bd >> 1, dir = bd & 1;
  int l0 = lg * 2;
  int t = threadIdx.x;
  int pi = t >> 4, qi = t & 15;
  __shared__ float xp[S_][75];
  __shared__ float xq[S_][75];
  __shared__ float w2s[2][H_];
  __shared__ float pn[2][S_], qn[2][S_];
  float (*cosT0)[S_ + 1] = (float (*)[S_ + 1])&xp[0][0];  // 4160 <= 4800 floats
  float (*cosT1)[S_ + 1] = (float (*)[S_ + 1])&xq[0][0];
  const float* w2g = w2 + (size_t)(2 + dir) * L_ * H_ + (size_t)l0 * H_;
  for (int idx = t; idx < 2 * H_; idx += 256) w2s[idx / H_][idx % H_] = w2g[idx];
  float dot[2][16];
#pragma unroll
  for (int l = 0; l < 2; ++l)
#pragma unroll
    for (int k = 0; k < 16; ++k) dot[l][k] = 0.f;
  float np2[2] = {0.f, 0.f}, nq2[2] = {0.f, 0.f};
  const float* Pb = P + (size_t)b * S_ * H2_ + dir * H_;
  const float* Qb = Q + (size_t)b * S_ * H2_ + dir * H_;
  for (int c0 = 0; c0 < H_; c0 += 75) {
    __syncthreads();
    for (int idx = t; idx < S_ * 75; idx += 256) {
      int s = idx / 75, hh = idx - s * 75;
      xp[s][hh] = Pb[(size_t)s * H2_ + c0 + hh];
      xq[s][hh] = Qb[(size_t)s * H2_ + c0 + hh];
    }
    __syncthreads();
    for (int hh = 0; hh < 75; ++hh) {
      float w0 = w2s[0][c0 + hh], w1 = w2s[1][c0 + hh];
      float pv[4], qv[4];
#pragma unroll
      for (int i = 0; i < 4; ++i) pv[i] = xp[pi + 16 * i][hh];   // 4 broadcast addrs
#pragma unroll
      for (int j = 0; j < 4; ++j) qv[j] = xq[qi + 16 * j][hh];   // stride 75: 16 distinct banks
      float p0[4], p1[4];
#pragma unroll
      for (int i = 0; i < 4; ++i) { p0[i] = pv[i] * w0; p1[i] = pv[i] * w1; }
#pragma unroll
      for (int i = 0; i < 4; ++i)
#pragma unroll
        for (int j = 0; j < 4; ++j) {
          dot[0][i * 4 + j] = fmaf(p0[i], qv[j], dot[0][i * 4 + j]);
          dot[1][i * 4 + j] = fmaf(p1[i], qv[j], dot[1][i * 4 + j]);
        }
    }
    if (t < S_) {
      for (int hh = 0; hh < 75; ++hh) {
        float v = xp[t][hh], vv = v * v;
        np2[0] = fmaf(w2s[0][c0 + hh], vv, np2[0]);
        np2[1] = fmaf(w2s[1][c0 + hh], vv, np2[1]);
      }
    } else if (t < 2 * S_) {
      int s2 = t - S_;
      for (int hh = 0; hh < 75; ++hh) {
        float v = xq[s2][hh], vv = v * v;
        nq2[0] = fmaf(w2s[0][c0 + hh], vv, nq2[0]);
        nq2[1] = fmaf(w2s[1][c0 + hh], vv, nq2[1]);
      }
    }
  }
  if (t < S_) { pn[0][t] = sqrtf(np2[0]); pn[1][t] = sqrtf(np2[1]); }
  else if (t < 2 * S_) { qn[0][t - S_] = sqrtf(nq2[0]); qn[1][t - S_] = sqrtf(nq2[1]); }
  __syncthreads();   // separates last xp/xq reads from cosT alias writes
#pragma unroll
  for (int i = 0; i < 4; ++i) {
    int p = pi + 16 * i;
#pragma unroll
    for (int j = 0; j < 4; ++j) {
      int q = qi + 16 * j;
      cosT0[p][q] = dot[0][i * 4 + j] / (pn[0][p] * qn[0][q]);
      cosT1[p][q] = dot[1][i * 4 + j] / (pn[1][p] * qn[1][q]);
    }
  }
  __syncthreads();
  if (t < S_) {            // out_p[s=t] = max over q
    float m0 = NEG_INF, m1 = NEG_INF;
    for (int q = 0; q < S_; ++q) { m0 = fmaxf(m0, cosT0[t][q]); m1 = fmaxf(m1, cosT1[t][q]); }
    size_t base = ((size_t)b * S_ + t) * ROW_ + (2 + dir) * L_ + l0;
    out[base] = m0; out[base + 1] = m1;
  } else if (t < 2 * S_) { // out_q[s] = max over p
    int s2 = t - S_;
    float m0 = NEG_INF, m1 = NEG_INF;
    for (int p = 0; p < S_; ++p) { m0 = fmaxf(m0, cosT0[p][s2]); m1 = fmaxf(m1, cosT1[p][s2]); }
    size_t base = OUTQ_OFF + ((size_t)b * S_ + s2) * ROW_ + (2 + dir) * L_ + l0;
    out[base] = m0; out[base + 1] = m1;
  }
}

// ---------------- K3: attentive vectors, computed ONCE per (bd, h-chunk).
// Same math/order as the r5/r6-passing fused version; LDS-staged inputs.
#define HC2 60
__global__ __launch_bounds__(256) void k_vecs(const float* __restrict__ P,
                                              const float* __restrict__ Q,
                                              const float* __restrict__ cosM,
                                              const float* __restrict__ sum_p,
                                              const float* __restrict__ sum_q,
                                              float* __restrict__ pvm, float* __restrict__ qvm,
                                              float* __restrict__ pvx, float* __restrict__ qvx) {
  int bd = blockIdx.x;
  int b = bd >> 1, dir = bd & 1;
  int h0 = blockIdx.y * HC2;
  __shared__ float cosL[S_][S_ + 1];
  __shared__ float xp[S_][HC2 + 1];
  __shared__ float xq[S_][HC2 + 1];
  __shared__ float sp[S_], sq[S_];
  int t = threadIdx.x;
  const float* cm = cosM + (size_t)bd * S_ * S_;
  for (int idx = t; idx < S_ * S_; idx += 256) cosL[idx >> 6][idx & 63] = cm[idx];
  if (t < S_) { sp[t] = sum_p[bd * S_ + t]; sq[t] = sum_q[bd * S_ + t]; }
  const float* Pb = P + (size_t)b * S_ * H2_ + dir * H_ + h0;
  const float* Qb = Q + (size_t)b * S_ * H2_ + dir * H_ + h0;
  for (int idx = t; idx < S_ * HC2; idx += 256) {
    int s = idx / HC2, hh = idx - s * HC2;
    xp[s][hh] = Pb[(size_t)s * H2_ + hh];
    xq[s][hh] = Qb[(size_t)s * H2_ + hh];
  }
  __syncthreads();
  size_t vb = (size_t)bd * S_ * H_;
  for (int idx = t; idx < S_ * HC2; idx += 256) {
    int s = idx / HC2, hh = idx - s * HC2;
    float am_p = 0.f, am_q = 0.f, ax_p = NEG_INF, ax_q = NEG_INF;
    for (int k = 0; k < S_; ++k) {
      float t1 = xp[k][hh] * cosL[k][s];   // p_vec candidates at q=s
      am_p += t1; ax_p = fmaxf(ax_p, t1);
      float t2 = xq[k][hh] * cosL[s][k];   // q_vec candidates at p=s
      am_q += t2; ax_q = fmaxf(ax_q, t2);
    }
    size_t o = vb + (size_t)s * H_ + h0 + hh;
    pvm[o] = am_p / sp[s];
    qvm[o] = am_q / sq[s];
    pvx[o] = ax_p;
    qvx[o] = ax_q;
  }
}

// ---------------- K4: final outputs (pieces 0,1,4,5,6,7). One block per (bd,s);
// vectors loaded coalesced from ws (no recompute).
__global__ __launch_bounds__(256) void k_outs(const float* __restrict__ P,
                                              const float* __restrict__ Q,
                                              const float* __restrict__ w2,
                                              const float* __restrict__ pvm,
                                              const float* __restrict__ qvm,
                                              const float* __restrict__ pvx,
                                              const float* __restrict__ qvx,
                                              float* __restrict__ out) {
  int bd = blockIdx.x >> 6;
  int s = blockIdx.x & 63;
  int b = bd >> 1, dir = bd & 1;
  int t = threadIdx.x;
  __shared__ float v8[8][H_];    // 0 xP, 1 xQ, 2 tQ, 3 tP, 4 qvm, 5 pvm, 6 qvx, 7 pvx
  size_t vb = (size_t)bd * S_ * H_ + (size_t)s * H_;
  int tgt = dir ? 0 : S_ - 1;
  const float* Pb = P + (size_t)b * S_ * H2_ + dir * H_;
  const float* Qb = Q + (size_t)b * S_ * H2_ + dir * H_;
  for (int idx = t; idx < 8 * H_; idx += 256) {
    int a = idx / H_, h = idx - a * H_;
    float v;
    switch (a) {
      case 0:  v = Pb[(size_t)s * H2_ + h]; break;
      case 1:  v = Qb[(size_t)s * H2_ + h]; break;
      case 2:  v = Qb[(size_t)tgt * H2_ + h]; break;
      case 3:  v = Pb[(size_t)tgt * H2_ + h]; break;
      case 4:  v = qvm[vb + h]; break;
      case 5:  v = pvm[vb + h]; break;
      case 6:  v = qvx[vb + h]; break;
      default: v = pvx[vb + h]; break;
    }
    v8[a][h] = v;
  }
  __syncthreads();
  if (t < 120) {
    int pr = t / L_, l = t - pr * L_;
    // pr: 0 p.tq W0  1 q.tp W0  2 p.qvm W4  3 q.pvm W4  4 p.qvx W6  5 q.pvx W6
    const int yi_[6] = {2, 3, 4, 5, 6, 7};
    const int wb_[6] = {0, 0, 4, 4, 6, 6};
    const float* x = v8[pr & 1];
    const float* y = v8[yi_[pr]];
    int widx = wb_[pr] + dir;
    const float* wp = w2 + (size_t)widx * (L_ * H_) + (size_t)l * H_;
    float a1 = 0.f, a2 = 0.f, a3 = 0.f;
    for (int h = 0; h < H_; ++h) {
      float wv = wp[h];
      float xx = x[h], yy = y[h];
      float wx = wv * xx;
      a1 = fmaf(wx, yy, a1);
      a2 = fmaf(wx, xx, a2);
      a3 = fmaf(wv * yy, yy, a3);
    }
    float den = fmaxf(sqrtf(a2) * sqrtf(a3), 1e-8f);   // EPS per _mp_cos
    float c = a1 / den;
    size_t base = ((pr & 1) ? OUTQ_OFF : 0) + ((size_t)b * S_ + s) * ROW_;
    out[base + (size_t)(wb_[pr] + dir) * L_ + l] = c;
  }
}

extern "C" void kernel_launch(void* const* d_in, const int* in_sizes, int n_in,
                              void* d_out, int out_size, void* d_ws, size_t ws_size,
                              hipStream_t stream) {
  (void)out_size; (void)ws_size;
  int iw = 2;
  for (int i = 0; i < n_in; ++i) if (in_sizes[i] == 8 * L_ * H_) iw = i;
  int io[2] = {0, 1}, k = 0;
  for (int i = 0; i < n_in && k < 2; ++i) if (i != iw) io[k++] = i;
  const float* P  = (const float*)d_in[io[0]];
  const float* Q  = (const float*)d_in[io[1]];
  const float* Wf = (const float*)d_in[iw];
  float* out = (float*)d_out;

  float* ws = (float*)d_ws;         // ~21 MB total (31 MB proven safe in r2/r3)
  float* w2    = ws;                // 48000
  float* cosM  = w2 + 48000;        // 262144
  float* sum_p = cosM + 262144;     // 4096
  float* sum_q = sum_p + 4096;      // 4096
  float* pvm   = sum_q + 4096;      // 1228800
  float* qvm   = pvm + 1228800;
  float* pvx   = qvm + 1228800;
  float* qvx   = pvx + 1228800;

  k_w2<<<(8 * L_ * H_ + 255) / 256, 256, 0, stream>>>(Wf, w2);
  k_cos<<<B_ * 2, 256, 0, stream>>>(P, Q, cosM, sum_p, sum_q);
  k_maxpool<<<B_ * 2 * 10, 256, 0, stream>>>(P, Q, w2, out);
  k_vecs<<<dim3(B_ * 2, 5), 256, 0, stream>>>(P, Q, cosM, sum_p, sum_q, pvm, qvm, pvx, qvx);
  k_outs<<<B_ * 2 * S_, 256, 0, stream>>>(P, Q, w2, pvm, qvm, pvx, qvx, out);
}

// Round 8
// 251.558 us; speedup vs baseline: 1.1010x; 1.1010x over previous
//
#include <hip/hip_runtime.h>
#include <hip/hip_bf16.h>

#define B_ 32
#define S_ 64
#define H_ 300
#define H2_ 600
#define L_ 20
#define ROW_ 160                    // 8 pieces * 20
#define OUTQ_OFF ((size_t)B_ * S_ * ROW_)
#define NEG_INF -3.402823466e38f

// ---------------- K0: w^2 tables: row [widx][l][h] (maxpool) + transposed [widx][h][l] (outs)
__global__ void k_w2(const float* __restrict__ Wf, float* __restrict__ w2,
                     float* __restrict__ w2t) {
  int i = blockIdx.x * 256 + threadIdx.x;
  if (i < 8 * L_ * H_) {
    float v = Wf[i];
    float v2 = v * v;
    w2[i] = v2;
    int widx = i / (L_ * H_);
    int r = i - widx * (L_ * H_);
    int l = r / H_;
    int h = r - l * H_;
    w2t[widx * (L_ * H_) + h * L_ + l] = v2;
  }
}

// ---------------- K1: plain cosine matrix per (b,dir) + fp64 row/col sums.
// R8: 4x4 register tile, conflict-free pi+16i / qi+16j swizzle.
__global__ __launch_bounds__(256) void k_cos(const float* __restrict__ P,
                                             const float* __restrict__ Q,
                                             float* __restrict__ cosM,
                                             float* __restrict__ sum_p,
                                             float* __restrict__ sum_q) {
  int bd = blockIdx.x;
  int b = bd >> 1, dir = bd & 1;
  __shared__ float xp[S_][101];
  __shared__ float xq[S_][101];
  __shared__ float pn[S_], qn[S_];
  __shared__ float cosL[S_][S_ + 1];
  int t = threadIdx.x;
  int pi = t >> 4, qi = t & 15;
  float dot[16];
#pragma unroll
  for (int k = 0; k < 16; ++k) dot[k] = 0.f;
  float np2 = 0.f, nq2 = 0.f;
  const float* Pb = P + (size_t)b * S_ * H2_ + dir * H_;
  const float* Qb = Q + (size_t)b * S_ * H2_ + dir * H_;
  for (int c0 = 0; c0 < H_; c0 += 100) {
    __syncthreads();
    for (int idx = t; idx < S_ * 100; idx += 256) {
      int s = idx / 100, hh = idx - s * 100;
      xp[s][hh] = Pb[(size_t)s * H2_ + c0 + hh];
      xq[s][hh] = Qb[(size_t)s * H2_ + c0 + hh];
    }
    __syncthreads();
    for (int hh = 0; hh < 100; ++hh) {
      float pv[4], qv[4];
#pragma unroll
      for (int i = 0; i < 4; ++i) pv[i] = xp[pi + 16 * i][hh];
#pragma unroll
      for (int j = 0; j < 4; ++j) qv[j] = xq[qi + 16 * j][hh];
#pragma unroll
      for (int i = 0; i < 4; ++i)
#pragma unroll
        for (int j = 0; j < 4; ++j) dot[i * 4 + j] = fmaf(pv[i], qv[j], dot[i * 4 + j]);
    }
    if (t < S_) {
      for (int hh = 0; hh < 100; ++hh) { float v = xp[t][hh]; np2 = fmaf(v, v, np2); }
    } else if (t < 2 * S_) {
      int s2 = t - S_;
      for (int hh = 0; hh < 100; ++hh) { float v = xq[s2][hh]; nq2 = fmaf(v, v, nq2); }
    }
  }
  if (t < S_) pn[t] = sqrtf(np2);
  else if (t < 2 * S_) qn[t - S_] = sqrtf(nq2);
  __syncthreads();
  float* cm = cosM + (size_t)bd * S_ * S_;
#pragma unroll
  for (int i = 0; i < 4; ++i) {
    int p = pi + 16 * i;
#pragma unroll
    for (int j = 0; j < 4; ++j) {
      int q = qi + 16 * j;
      float c = dot[i * 4 + j] / (pn[p] * qn[q]);
      cosL[p][q] = c;
      cm[p * S_ + q] = c;
    }
  }
  __syncthreads();
  if (t < S_) {            // sum over p at q=t  (cos.sum(axis=1))
    double acc = 0.0;
    for (int p = 0; p < S_; ++p) acc += (double)cosL[p][t];
    sum_p[bd * S_ + t] = (float)acc;
  } else if (t < 2 * S_) { // sum over q at p=t-64  (cos.sum(axis=2))
    int r = t - S_;
    double acc = 0.0;
    for (int q = 0; q < S_; ++q) acc += (double)cosL[r][q];
    sum_q[bd * S_ + r] = (float)acc;
  }
}

// ---------------- K2: maxpool matching (byte-identical to r7: 88 us, ~0 conflicts)
__global__ __launch_bounds__(256) void k_maxpool(const float* __restrict__ P,
                                                 const float* __restrict__ Q,
                                                 const float* __restrict__ w2,
                                                 float* __restrict__ out) {
  int lg = blockIdx.x % 10;
  int bd = blockIdx.x / 10;
  int b = bd >> 1, dir = bd & 1;
  int l0 = lg * 2;
  int t = threadIdx.x;
  int pi = t >> 4, qi = t & 15;
  __shared__ float xp[S_][75];
  __shared__ float xq[S_][75];
  __shared__ float w2s[2][H_];
  __shared__ float pn[2][S_], qn[2][S_];
  float (*cosT0)[S_ + 1] = (float (*)[S_ + 1])&xp[0][0];
  float (*cosT1)[S_ + 1] = (float (*)[S_ + 1])&xq[0][0];
  const float* w2g = w2 + (size_t)(2 + dir) * L_ * H_ + (size_t)l0 * H_;
  for (int idx = t; idx < 2 * H_; idx += 256) w2s[idx / H_][idx % H_] = w2g[idx];
  float dot[2][16];
#pragma unroll
  for (int l = 0; l < 2; ++l)
#pragma unroll
    for (int k = 0; k < 16; ++k) dot[l][k] = 0.f;
  float np2[2] = {0.f, 0.f}, nq2[2] = {0.f, 0.f};
  const float* Pb = P + (size_t)b * S_ * H2_ + dir * H_;
  const float* Qb = Q + (size_t)b * S_ * H2_ + dir * H_;
  for (int c0 = 0; c0 < H_; c0 += 75) {
    __syncthreads();
    for (int idx = t; idx < S_ * 75; idx += 256) {
      int s = idx / 75, hh = idx - s * 75;
      xp[s][hh] = Pb[(size_t)s * H2_ + c0 + hh];
      xq[s][hh] = Qb[(size_t)s * H2_ + c0 + hh];
    }
    __syncthreads();
    for (int hh = 0; hh < 75; ++hh) {
      float w0 = w2s[0][c0 + hh], w1 = w2s[1][c0 + hh];
      float pv[4], qv[4];
#pragma unroll
      for (int i = 0; i < 4; ++i) pv[i] = xp[pi + 16 * i][hh];
#pragma unroll
      for (int j = 0; j < 4; ++j) qv[j] = xq[qi + 16 * j][hh];
      float p0[4], p1[4];
#pragma unroll
      for (int i = 0; i < 4; ++i) { p0[i] = pv[i] * w0; p1[i] = pv[i] * w1; }
#pragma unroll
      for (int i = 0; i < 4; ++i)
#pragma unroll
        for (int j = 0; j < 4; ++j) {
          dot[0][i * 4 + j] = fmaf(p0[i], qv[j], dot[0][i * 4 + j]);
          dot[1][i * 4 + j] = fmaf(p1[i], qv[j], dot[1][i * 4 + j]);
        }
    }
    if (t < S_) {
      for (int hh = 0; hh < 75; ++hh) {
        float v = xp[t][hh], vv = v * v;
        np2[0] = fmaf(w2s[0][c0 + hh], vv, np2[0]);
        np2[1] = fmaf(w2s[1][c0 + hh], vv, np2[1]);
      }
    } else if (t < 2 * S_) {
      int s2 = t - S_;
      for (int hh = 0; hh < 75; ++hh) {
        float v = xq[s2][hh], vv = v * v;
        nq2[0] = fmaf(w2s[0][c0 + hh], vv, nq2[0]);
        nq2[1] = fmaf(w2s[1][c0 + hh], vv, nq2[1]);
      }
    }
  }
  if (t < S_) { pn[0][t] = sqrtf(np2[0]); pn[1][t] = sqrtf(np2[1]); }
  else if (t < 2 * S_) { qn[0][t - S_] = sqrtf(nq2[0]); qn[1][t - S_] = sqrtf(nq2[1]); }
  __syncthreads();
#pragma unroll
  for (int i = 0; i < 4; ++i) {
    int p = pi + 16 * i;
#pragma unroll
    for (int j = 0; j < 4; ++j) {
      int q = qi + 16 * j;
      cosT0[p][q] = dot[0][i * 4 + j] / (pn[0][p] * qn[0][q]);
      cosT1[p][q] = dot[1][i * 4 + j] / (pn[1][p] * qn[1][q]);
    }
  }
  __syncthreads();
  if (t < S_) {
    float m0 = NEG_INF, m1 = NEG_INF;
    for (int q = 0; q < S_; ++q) { m0 = fmaxf(m0, cosT0[t][q]); m1 = fmaxf(m1, cosT1[t][q]); }
    size_t base = ((size_t)b * S_ + t) * ROW_ + (2 + dir) * L_ + l0;
    out[base] = m0; out[base + 1] = m1;
  } else if (t < 2 * S_) {
    int s2 = t - S_;
    float m0 = NEG_INF, m1 = NEG_INF;
    for (int p = 0; p < S_; ++p) { m0 = fmaxf(m0, cosT0[p][s2]); m1 = fmaxf(m1, cosT1[p][s2]); }
    size_t base = OUTQ_OFF + ((size_t)b * S_ + s2) * ROW_ + (2 + dir) * L_ + l0;
    out[base] = m0; out[base + 1] = m1;
  }
}

// ---------------- K3: FUSED attentive vectors + outputs, 8 s per block.
// Same per-s formulas as the r5/r6-passing fused kernel; k-loop amortized 8x.
#define SG 8
__global__ __launch_bounds__(256) void k_outs(const float* __restrict__ P,
                                              const float* __restrict__ Q,
                                              const float* __restrict__ w2t,
                                              const float* __restrict__ cosM,
                                              const float* __restrict__ sum_p,
                                              const float* __restrict__ sum_q,
                                              float* __restrict__ out) {
  int bd = blockIdx.x >> 3;
  int sg = blockIdx.x & 7;
  int s0 = sg * SG;
  int b = bd >> 1, dir = bd & 1;
  int t = threadIdx.x;
  __shared__ float cosC[SG][S_];   // cos[p][s0+si]
  __shared__ float cosR[SG][S_];   // cos[s0+si][q]
  __shared__ float tq[H_], tp[H_];
  __shared__ float xP[SG][H_], xQ[SG][H_];
  __shared__ float vmq[SG][H_], vmp[SG][H_], vxq[SG][H_], vxp[SG][H_];
  __shared__ float sps[SG], sqs[SG];
  const float* cm = cosM + (size_t)bd * S_ * S_;
  for (int idx = t; idx < SG * S_; idx += 256) {
    int si = idx >> 6, k = idx & 63;
    cosC[si][k] = cm[k * S_ + s0 + si];
    cosR[si][k] = cm[(s0 + si) * S_ + k];
  }
  if (t < SG) { sps[t] = sum_p[bd * S_ + s0 + t]; sqs[t] = sum_q[bd * S_ + s0 + t]; }
  int tgt = dir ? 0 : S_ - 1;
  const float* Pb = P + (size_t)b * S_ * H2_ + dir * H_;
  const float* Qb = Q + (size_t)b * S_ * H2_ + dir * H_;
  for (int h = t; h < H_; h += 256) { tq[h] = Qb[(size_t)tgt * H2_ + h]; tp[h] = Pb[(size_t)tgt * H2_ + h]; }
  for (int idx = t; idx < SG * H_; idx += 256) {
    int si = idx / H_, h = idx - si * H_;
    xP[si][h] = Pb[(size_t)(s0 + si) * H2_ + h];
    xQ[si][h] = Qb[(size_t)(s0 + si) * H2_ + h];
  }
  __syncthreads();
  // Phase B: attention vectors for the 8 s values, k-loop loads shared.
  for (int h = t; h < H_; h += 256) {
    float amp[SG], amq[SG], axp[SG], axq[SG];
#pragma unroll
    for (int si = 0; si < SG; ++si) { amp[si] = 0.f; amq[si] = 0.f; axp[si] = NEG_INF; axq[si] = NEG_INF; }
    for (int k = 0; k < S_; ++k) {
      float pv = Pb[(size_t)k * H2_ + h];
      float qv = Qb[(size_t)k * H2_ + h];
#pragma unroll
      for (int si = 0; si < SG; ++si) {
        float t1 = pv * cosC[si][k];   // p_vec candidates at q=s
        amp[si] += t1; axp[si] = fmaxf(axp[si], t1);
        float t2 = qv * cosR[si][k];   // q_vec candidates at p=s
        amq[si] += t2; axq[si] = fmaxf(axq[si], t2);
      }
    }
#pragma unroll
    for (int si = 0; si < SG; ++si) {
      vmq[si][h] = amq[si] / sqs[si];
      vmp[si][h] = amp[si] / sps[si];
      vxq[si][h] = axq[si];
      vxp[si][h] = axp[si];
    }
  }
  __syncthreads();
  // Phase C: 8 si * 6 pr * 20 l = 960 weighted cosines; 240 threads * 4 jobs.
  if (t < 240) {
    const int wb_[6] = {0, 0, 4, 4, 6, 6};
#pragma unroll
    for (int r = 0; r < 4; ++r) {
      int job = t + 240 * r;
      int l = job % L_;
      int g = job / L_;          // 0..47
      int pr = g % 6, si = g / 6;
      const float* x = (pr & 1) ? xQ[si] : xP[si];
      const float* y;
      if (pr == 0) y = tq;
      else if (pr == 1) y = tp;
      else if (pr == 2) y = vmq[si];
      else if (pr == 3) y = vmp[si];
      else if (pr == 4) y = vxq[si];
      else y = vxp[si];
      int widx = wb_[pr] + dir;
      const float* wp = w2t + (size_t)widx * (L_ * H_) + l;   // [h][l]: 20-lane groups coalesced
      float a1 = 0.f, a2 = 0.f, a3 = 0.f;
      for (int h = 0; h < H_; ++h) {
        float wv = wp[h * L_];
        float xx = x[h], yy = y[h];
        float wx = wv * xx;
        a1 = fmaf(wx, yy, a1);
        a2 = fmaf(wx, xx, a2);
        a3 = fmaf(wv * yy, yy, a3);
      }
      float den = fmaxf(sqrtf(a2) * sqrtf(a3), 1e-8f);   // EPS per _mp_cos
      float c = a1 / den;
      int s = s0 + si;
      size_t base = ((pr & 1) ? OUTQ_OFF : 0) + ((size_t)b * S_ + s) * ROW_;
      out[base + (size_t)widx * L_ + l] = c;
    }
  }
}

extern "C" void kernel_launch(void* const* d_in, const int* in_sizes, int n_in,
                              void* d_out, int out_size, void* d_ws, size_t ws_size,
                              hipStream_t stream) {
  (void)out_size; (void)ws_size;
  int iw = 2;
  for (int i = 0; i < n_in; ++i) if (in_sizes[i] == 8 * L_ * H_) iw = i;
  int io[2] = {0, 1}, k = 0;
  for (int i = 0; i < n_in && k < 2; ++i) if (i != iw) io[k++] = i;
  const float* P  = (const float*)d_in[io[0]];
  const float* Q  = (const float*)d_in[io[1]];
  const float* Wf = (const float*)d_in[iw];
  float* out = (float*)d_out;

  float* ws = (float*)d_ws;         // ~1.46 MB
  float* w2    = ws;                // 48000
  float* w2t   = w2 + 48000;        // 48000
  float* cosM  = w2t + 48000;       // 262144
  float* sum_p = cosM + 262144;     // 4096
  float* sum_q = sum_p + 4096;      // 4096

  k_w2<<<(8 * L_ * H_ + 255) / 256, 256, 0, stream>>>(Wf, w2, w2t);
  k_cos<<<B_ * 2, 256, 0, stream>>>(P, Q, cosM, sum_p, sum_q);
  k_maxpool<<<B_ * 2 * 10, 256, 0, stream>>>(P, Q, w2, out);
  k_outs<<<B_ * 2 * 8, 256, 0, stream>>>(P, Q, w2t, cosM, sum_p, sum_q, out);
}

// Round 9
// 222.073 us; speedup vs baseline: 1.2472x; 1.1328x over previous
//
#include <hip/hip_runtime.h>
#include <hip/hip_bf16.h>

#define B_ 32
#define S_ 64
#define H_ 300
#define H2_ 600
#define L_ 20
#define ROW_ 160                    // 8 pieces * 20
#define OUTQ_OFF ((size_t)B_ * S_ * ROW_)
#define NEG_INF -3.402823466e38f

// ---------------- K0: w^2 tables: row [widx][l][h] (maxpool) + transposed [widx][h][l] (outs)
__global__ void k_w2(const float* __restrict__ Wf, float* __restrict__ w2,
                     float* __restrict__ w2t) {
  int i = blockIdx.x * 256 + threadIdx.x;
  if (i < 8 * L_ * H_) {
    float v = Wf[i];
    float v2 = v * v;
    w2[i] = v2;
    int widx = i / (L_ * H_);
    int r = i - widx * (L_ * H_);
    int l = r / H_;
    int h = r - l * H_;
    w2t[widx * (L_ * H_) + h * L_ + l] = v2;
  }
}

// ---------------- K1: plain cosine matrix per (b,dir) + fp64 row/col sums (r8: pass)
__global__ __launch_bounds__(256) void k_cos(const float* __restrict__ P,
                                             const float* __restrict__ Q,
                                             float* __restrict__ cosM,
                                             float* __restrict__ sum_p,
                                             float* __restrict__ sum_q) {
  int bd = blockIdx.x;
  int b = bd >> 1, dir = bd & 1;
  __shared__ float xp[S_][101];
  __shared__ float xq[S_][101];
  __shared__ float pn[S_], qn[S_];
  __shared__ float cosL[S_][S_ + 1];
  int t = threadIdx.x;
  int pi = t >> 4, qi = t & 15;
  float dot[16];
#pragma unroll
  for (int k = 0; k < 16; ++k) dot[k] = 0.f;
  float np2 = 0.f, nq2 = 0.f;
  const float* Pb = P + (size_t)b * S_ * H2_ + dir * H_;
  const float* Qb = Q + (size_t)b * S_ * H2_ + dir * H_;
  for (int c0 = 0; c0 < H_; c0 += 100) {
    __syncthreads();
    for (int idx = t; idx < S_ * 100; idx += 256) {
      int s = idx / 100, hh = idx - s * 100;
      xp[s][hh] = Pb[(size_t)s * H2_ + c0 + hh];
      xq[s][hh] = Qb[(size_t)s * H2_ + c0 + hh];
    }
    __syncthreads();
    for (int hh = 0; hh < 100; ++hh) {
      float pv[4], qv[4];
#pragma unroll
      for (int i = 0; i < 4; ++i) pv[i] = xp[pi + 16 * i][hh];
#pragma unroll
      for (int j = 0; j < 4; ++j) qv[j] = xq[qi + 16 * j][hh];
#pragma unroll
      for (int i = 0; i < 4; ++i)
#pragma unroll
        for (int j = 0; j < 4; ++j) dot[i * 4 + j] = fmaf(pv[i], qv[j], dot[i * 4 + j]);
    }
    if (t < S_) {
      for (int hh = 0; hh < 100; ++hh) { float v = xp[t][hh]; np2 = fmaf(v, v, np2); }
    } else if (t < 2 * S_) {
      int s2 = t - S_;
      for (int hh = 0; hh < 100; ++hh) { float v = xq[s2][hh]; nq2 = fmaf(v, v, nq2); }
    }
  }
  if (t < S_) pn[t] = sqrtf(np2);
  else if (t < 2 * S_) qn[t - S_] = sqrtf(nq2);
  __syncthreads();
  float* cm = cosM + (size_t)bd * S_ * S_;
#pragma unroll
  for (int i = 0; i < 4; ++i) {
    int p = pi + 16 * i;
#pragma unroll
    for (int j = 0; j < 4; ++j) {
      int q = qi + 16 * j;
      float c = dot[i * 4 + j] / (pn[p] * qn[q]);
      cosL[p][q] = c;
      cm[p * S_ + q] = c;
    }
  }
  __syncthreads();
  if (t < S_) {
    double acc = 0.0;
    for (int p = 0; p < S_; ++p) acc += (double)cosL[p][t];
    sum_p[bd * S_ + t] = (float)acc;
  } else if (t < 2 * S_) {
    int r = t - S_;
    double acc = 0.0;
    for (int q = 0; q < S_; ++q) acc += (double)cosL[r][q];
    sum_q[bd * S_ + r] = (float)acc;
  }
}

// ======== fused main kernel: blocks [0,640) maxpool | [640, 640+1024) outs ========
struct MaxpoolS {              // 41824 B
  float xp[S_][75];
  float xq[S_][75];
  float w2s[2][H_];
  float pn[2][S_], qn[2][S_];
};
#define SG 4
struct OutsS {                 // 33312 B
  float cosC[SG][S_];
  float cosR[SG][S_];
  float tq[H_], tp[H_];
  float xP[SG][H_], xQ[SG][H_];
  float vmq[SG][H_], vmp[SG][H_], vxq[SG][H_], vxp[SG][H_];
  float sps[SG], sqs[SG];
};

__device__ __forceinline__ void maxpool_body(char* smem, int bid,
                                             const float* __restrict__ P,
                                             const float* __restrict__ Q,
                                             const float* __restrict__ w2,
                                             float* __restrict__ out) {
  MaxpoolS& S = *(MaxpoolS*)smem;
  int lg = bid % 10;
  int bd = bid / 10;
  int b = bd >> 1, dir = bd & 1;
  int l0 = lg * 2;
  int t = threadIdx.x;
  int pi = t >> 4, qi = t & 15;
  float (*cosT0)[S_ + 1] = (float (*)[S_ + 1])&S.xp[0][0];  // 4160 <= 4800
  float (*cosT1)[S_ + 1] = (float (*)[S_ + 1])&S.xq[0][0];
  const float* w2g = w2 + (size_t)(2 + dir) * L_ * H_ + (size_t)l0 * H_;
  for (int idx = t; idx < 2 * H_; idx += 256) S.w2s[idx / H_][idx % H_] = w2g[idx];
  float dot[2][16];
#pragma unroll
  for (int l = 0; l < 2; ++l)
#pragma unroll
    for (int k = 0; k < 16; ++k) dot[l][k] = 0.f;
  float np2[2] = {0.f, 0.f}, nq2[2] = {0.f, 0.f};
  const float* Pb = P + (size_t)b * S_ * H2_ + dir * H_;
  const float* Qb = Q + (size_t)b * S_ * H2_ + dir * H_;
  for (int c0 = 0; c0 < H_; c0 += 75) {
    __syncthreads();
    for (int idx = t; idx < S_ * 75; idx += 256) {
      int s = idx / 75, hh = idx - s * 75;
      S.xp[s][hh] = Pb[(size_t)s * H2_ + c0 + hh];
      S.xq[s][hh] = Qb[(size_t)s * H2_ + c0 + hh];
    }
    __syncthreads();
    for (int hh = 0; hh < 75; ++hh) {
      float w0 = S.w2s[0][c0 + hh], w1 = S.w2s[1][c0 + hh];
      float pv[4], qv[4];
#pragma unroll
      for (int i = 0; i < 4; ++i) pv[i] = S.xp[pi + 16 * i][hh];
#pragma unroll
      for (int j = 0; j < 4; ++j) qv[j] = S.xq[qi + 16 * j][hh];
      float p0[4], p1[4];
#pragma unroll
      for (int i = 0; i < 4; ++i) { p0[i] = pv[i] * w0; p1[i] = pv[i] * w1; }
#pragma unroll
      for (int i = 0; i < 4; ++i)
#pragma unroll
        for (int j = 0; j < 4; ++j) {
          dot[0][i * 4 + j] = fmaf(p0[i], qv[j], dot[0][i * 4 + j]);
          dot[1][i * 4 + j] = fmaf(p1[i], qv[j], dot[1][i * 4 + j]);
        }
    }
    if (t < S_) {
      for (int hh = 0; hh < 75; ++hh) {
        float v = S.xp[t][hh], vv = v * v;
        np2[0] = fmaf(S.w2s[0][c0 + hh], vv, np2[0]);
        np2[1] = fmaf(S.w2s[1][c0 + hh], vv, np2[1]);
      }
    } else if (t < 2 * S_) {
      int s2 = t - S_;
      for (int hh = 0; hh < 75; ++hh) {
        float v = S.xq[s2][hh], vv = v * v;
        nq2[0] = fmaf(S.w2s[0][c0 + hh], vv, nq2[0]);
        nq2[1] = fmaf(S.w2s[1][c0 + hh], vv, nq2[1]);
      }
    }
  }
  if (t < S_) { S.pn[0][t] = sqrtf(np2[0]); S.pn[1][t] = sqrtf(np2[1]); }
  else if (t < 2 * S_) { S.qn[0][t - S_] = sqrtf(nq2[0]); S.qn[1][t - S_] = sqrtf(nq2[1]); }
  __syncthreads();
#pragma unroll
  for (int i = 0; i < 4; ++i) {
    int p = pi + 16 * i;
#pragma unroll
    for (int j = 0; j < 4; ++j) {
      int q = qi + 16 * j;
      cosT0[p][q] = dot[0][i * 4 + j] / (S.pn[0][p] * S.qn[0][q]);
      cosT1[p][q] = dot[1][i * 4 + j] / (S.pn[1][p] * S.qn[1][q]);
    }
  }
  __syncthreads();
  if (t < S_) {
    float m0 = NEG_INF, m1 = NEG_INF;
    for (int q = 0; q < S_; ++q) { m0 = fmaxf(m0, cosT0[t][q]); m1 = fmaxf(m1, cosT1[t][q]); }
    size_t base = ((size_t)b * S_ + t) * ROW_ + (2 + dir) * L_ + l0;
    out[base] = m0; out[base + 1] = m1;
  } else if (t < 2 * S_) {
    int s2 = t - S_;
    float m0 = NEG_INF, m1 = NEG_INF;
    for (int p = 0; p < S_; ++p) { m0 = fmaxf(m0, cosT0[p][s2]); m1 = fmaxf(m1, cosT1[p][s2]); }
    size_t base = OUTQ_OFF + ((size_t)b * S_ + s2) * ROW_ + (2 + dir) * L_ + l0;
    out[base] = m0; out[base + 1] = m1;
  }
}

__device__ __forceinline__ void outs_body(char* smem, int bid,
                                          const float* __restrict__ P,
                                          const float* __restrict__ Q,
                                          const float* __restrict__ w2t,
                                          const float* __restrict__ cosM,
                                          const float* __restrict__ sum_p,
                                          const float* __restrict__ sum_q,
                                          float* __restrict__ out) {
  OutsS& S = *(OutsS*)smem;
  int bd = bid >> 4;           // 16 s-groups of 4
  int sg = bid & 15;
  int s0 = sg * SG;
  int b = bd >> 1, dir = bd & 1;
  int t = threadIdx.x;
  const float* cm = cosM + (size_t)bd * S_ * S_;
  for (int idx = t; idx < SG * S_; idx += 256) {
    int si = idx >> 6, k = idx & 63;
    S.cosC[si][k] = cm[k * S_ + s0 + si];
    S.cosR[si][k] = cm[(s0 + si) * S_ + k];
  }
  if (t < SG) { S.sps[t] = sum_p[bd * S_ + s0 + t]; S.sqs[t] = sum_q[bd * S_ + s0 + t]; }
  int tgt = dir ? 0 : S_ - 1;
  const float* Pb = P + (size_t)b * S_ * H2_ + dir * H_;
  const float* Qb = Q + (size_t)b * S_ * H2_ + dir * H_;
  for (int h = t; h < H_; h += 256) { S.tq[h] = Qb[(size_t)tgt * H2_ + h]; S.tp[h] = Pb[(size_t)tgt * H2_ + h]; }
  for (int idx = t; idx < SG * H_; idx += 256) {
    int si = idx / H_, h = idx - si * H_;
    S.xP[si][h] = Pb[(size_t)(s0 + si) * H2_ + h];
    S.xQ[si][h] = Qb[(size_t)(s0 + si) * H2_ + h];
  }
  __syncthreads();
  // Phase B: attention vectors for 4 s values; k-loop unrolled x2 for load ILP.
  for (int h = t; h < H_; h += 256) {
    float amp[SG], amq[SG], axp[SG], axq[SG];
#pragma unroll
    for (int si = 0; si < SG; ++si) { amp[si] = 0.f; amq[si] = 0.f; axp[si] = NEG_INF; axq[si] = NEG_INF; }
    for (int k = 0; k < S_; k += 2) {
      float pv0 = Pb[(size_t)k * H2_ + h];
      float qv0 = Qb[(size_t)k * H2_ + h];
      float pv1 = Pb[(size_t)(k + 1) * H2_ + h];
      float qv1 = Qb[(size_t)(k + 1) * H2_ + h];
#pragma unroll
      for (int si = 0; si < SG; ++si) {
        float t1 = pv0 * S.cosC[si][k];
        amp[si] += t1; axp[si] = fmaxf(axp[si], t1);
        float t2 = qv0 * S.cosR[si][k];
        amq[si] += t2; axq[si] = fmaxf(axq[si], t2);
        float t3 = pv1 * S.cosC[si][k + 1];
        amp[si] += t3; axp[si] = fmaxf(axp[si], t3);
        float t4 = qv1 * S.cosR[si][k + 1];
        amq[si] += t4; axq[si] = fmaxf(axq[si], t4);
      }
    }
#pragma unroll
    for (int si = 0; si < SG; ++si) {
      S.vmq[si][h] = amq[si] / S.sqs[si];
      S.vmp[si][h] = amp[si] / S.sps[si];
      S.vxq[si][h] = axq[si];
      S.vxp[si][h] = axp[si];
    }
  }
  __syncthreads();
  // Phase C: 4 si * 6 pr * 20 l = 480 jobs; 240 threads * 2.
  if (t < 240) {
    const int wb_[6] = {0, 0, 4, 4, 6, 6};
#pragma unroll
    for (int r = 0; r < 2; ++r) {
      int job = t + 240 * r;
      int l = job % L_;
      int g = job / L_;          // 0..23
      int pr = g % 6, si = g / 6;
      const float* x = (pr & 1) ? S.xQ[si] : S.xP[si];
      const float* y;
      if (pr == 0) y = S.tq;
      else if (pr == 1) y = S.tp;
      else if (pr == 2) y = S.vmq[si];
      else if (pr == 3) y = S.vmp[si];
      else if (pr == 4) y = S.vxq[si];
      else y = S.vxp[si];
      int widx = wb_[pr] + dir;
      const float* wp = w2t + (size_t)widx * (L_ * H_) + l;
      float a1 = 0.f, a2 = 0.f, a3 = 0.f;
      for (int h = 0; h < H_; ++h) {
        float wv = wp[h * L_];
        float xx = x[h], yy = y[h];
        float wx = wv * xx;
        a1 = fmaf(wx, yy, a1);
        a2 = fmaf(wx, xx, a2);
        a3 = fmaf(wv * yy, yy, a3);
      }
      float den = fmaxf(sqrtf(a2) * sqrtf(a3), 1e-8f);   // EPS per _mp_cos
      float c = a1 / den;
      int s = s0 + si;
      size_t base = ((pr & 1) ? OUTQ_OFF : 0) + ((size_t)b * S_ + s) * ROW_;
      out[base + (size_t)widx * L_ + l] = c;
    }
  }
}

__global__ __launch_bounds__(256) void k_main(const float* __restrict__ P,
                                              const float* __restrict__ Q,
                                              const float* __restrict__ w2,
                                              const float* __restrict__ w2t,
                                              const float* __restrict__ cosM,
                                              const float* __restrict__ sum_p,
                                              const float* __restrict__ sum_q,
                                              float* __restrict__ out) {
  extern __shared__ char smem[];
  int bid = blockIdx.x;
  if (bid < B_ * 2 * 10) maxpool_body(smem, bid, P, Q, w2, out);
  else outs_body(smem, bid - B_ * 2 * 10, P, Q, w2t, cosM, sum_p, sum_q, out);
}

extern "C" void kernel_launch(void* const* d_in, const int* in_sizes, int n_in,
                              void* d_out, int out_size, void* d_ws, size_t ws_size,
                              hipStream_t stream) {
  (void)out_size; (void)ws_size;
  int iw = 2;
  for (int i = 0; i < n_in; ++i) if (in_sizes[i] == 8 * L_ * H_) iw = i;
  int io[2] = {0, 1}, k = 0;
  for (int i = 0; i < n_in && k < 2; ++i) if (i != iw) io[k++] = i;
  const float* P  = (const float*)d_in[io[0]];
  const float* Q  = (const float*)d_in[io[1]];
  const float* Wf = (const float*)d_in[iw];
  float* out = (float*)d_out;

  float* ws = (float*)d_ws;         // ~1.46 MB
  float* w2    = ws;                // 48000
  float* w2t   = w2 + 48000;        // 48000
  float* cosM  = w2t + 48000;       // 262144
  float* sum_p = cosM + 262144;     // 4096
  float* sum_q = sum_p + 4096;      // 4096

  size_t shbytes = sizeof(MaxpoolS) > sizeof(OutsS) ? sizeof(MaxpoolS) : sizeof(OutsS);
  k_w2<<<(8 * L_ * H_ + 255) / 256, 256, 0, stream>>>(Wf, w2, w2t);
  k_cos<<<B_ * 2, 256, 0, stream>>>(P, Q, cosM, sum_p, sum_q);
  k_main<<<B_ * 2 * 10 + B_ * 2 * 16, 256, shbytes, stream>>>(P, Q, w2, w2t, cosM, sum_p, sum_q, out);
}

// Round 10
// 221.449 us; speedup vs baseline: 1.2507x; 1.0028x over previous
//
#include <hip/hip_runtime.h>
#include <hip/hip_bf16.h>

#define B_ 32
#define S_ 64
#define H_ 300
#define H2_ 600
#define L_ 20
#define ROW_ 160                    // 8 pieces * 20
#define OUTQ_OFF ((size_t)B_ * S_ * ROW_)
#define NEG_INF -3.402823466e38f

// ---------------- K0: w^2 tables + zero sum_p (atomic target in k_cos)
__global__ void k_w2(const float* __restrict__ Wf, float* __restrict__ w2,
                     float* __restrict__ w2t, float* __restrict__ sum_p) {
  int i = blockIdx.x * 256 + threadIdx.x;
  if (i < 8 * L_ * H_) {
    float v = Wf[i];
    float v2 = v * v;
    w2[i] = v2;
    int widx = i / (L_ * H_);
    int r = i - widx * (L_ * H_);
    int l = r / H_;
    int h = r - l * H_;
    w2t[widx * (L_ * H_) + h * L_ + l] = v2;
  }
  if (i < B_ * 2 * S_) sum_p[i] = 0.f;
}

// ---------------- K1: cosine matrix, 4x parallel: block = (bd, 16-row p-group).
// Row sums (over q) block-local fp64; col sums (over p) fp32 atomic partials.
__global__ __launch_bounds__(256) void k_cos(const float* __restrict__ P,
                                             const float* __restrict__ Q,
                                             float* __restrict__ cosM,
                                             float* __restrict__ sum_p,
                                             float* __restrict__ sum_q) {
  int bd = blockIdx.x;
  int pg = blockIdx.y;
  int p0 = pg * 16;
  int b = bd >> 1, dir = bd & 1;
  __shared__ float xp[16][101];
  __shared__ float xq[S_][101];    // stride 101: (5q+hh)%32, gcd(5,32)=1 -> 2-way free
  __shared__ float pn[16], qn[S_];
  __shared__ float cosL[16][S_ + 1];
  int t = threadIdx.x;
  int q = t & 63, pr = t >> 6;     // wave-uniform pr -> xp reads broadcast
  float dot[4] = {0.f, 0.f, 0.f, 0.f};
  float np2 = 0.f, nq2 = 0.f;
  const float* Pb = P + (size_t)b * S_ * H2_ + dir * H_;
  const float* Qb = Q + (size_t)b * S_ * H2_ + dir * H_;
  for (int c0 = 0; c0 < H_; c0 += 100) {
    __syncthreads();
    for (int idx = t; idx < 16 * 100; idx += 256) {
      int s = idx / 100, hh = idx - s * 100;
      xp[s][hh] = Pb[(size_t)(p0 + s) * H2_ + c0 + hh];
    }
    for (int idx = t; idx < S_ * 100; idx += 256) {
      int s = idx / 100, hh = idx - s * 100;
      xq[s][hh] = Qb[(size_t)s * H2_ + c0 + hh];
    }
    __syncthreads();
    for (int hh = 0; hh < 100; ++hh) {
      float qv = xq[q][hh];
#pragma unroll
      for (int i = 0; i < 4; ++i) dot[i] = fmaf(xp[pr + 4 * i][hh], qv, dot[i]);
    }
    if (t < 16) {
      for (int hh = 0; hh < 100; ++hh) { float v = xp[t][hh]; np2 = fmaf(v, v, np2); }
    } else if (t >= 64 && t < 128) {
      int s2 = t - 64;
      for (int hh = 0; hh < 100; ++hh) { float v = xq[s2][hh]; nq2 = fmaf(v, v, nq2); }
    }
  }
  if (t < 16) pn[t] = sqrtf(np2);
  else if (t >= 64 && t < 128) qn[t - 64] = sqrtf(nq2);
  __syncthreads();
  float* cm = cosM + (size_t)bd * S_ * S_;
#pragma unroll
  for (int i = 0; i < 4; ++i) {
    int p = pr + 4 * i;
    float c = dot[i] / (pn[p] * qn[q]);   // no EPS in reference attentive cos
    cosL[p][q] = c;
    cm[(size_t)(p0 + p) * S_ + q] = c;
  }
  __syncthreads();
  if (t < 16) {                    // full row sum over q (block owns rows p0..p0+15)
    double acc = 0.0;
    for (int qq = 0; qq < S_; ++qq) acc += (double)cosL[t][qq];
    sum_q[bd * S_ + p0 + t] = (float)acc;
  } else if (t >= 64 && t < 128) { // partial col sum over this block's 16 p
    int qq = t - 64;
    float acc = 0.f;
    for (int p = 0; p < 16; ++p) acc += cosL[p][qq];
    atomicAdd(&sum_p[bd * S_ + qq], acc);
  }
}

// ======== fused main kernel (byte-identical to r9: 148 us) ========
struct MaxpoolS {              // 41824 B
  float xp[S_][75];
  float xq[S_][75];
  float w2s[2][H_];
  float pn[2][S_], qn[2][S_];
};
#define SG 4
struct OutsS {                 // 33312 B
  float cosC[SG][S_];
  float cosR[SG][S_];
  float tq[H_], tp[H_];
  float xP[SG][H_], xQ[SG][H_];
  float vmq[SG][H_], vmp[SG][H_], vxq[SG][H_], vxp[SG][H_];
  float sps[SG], sqs[SG];
};

__device__ __forceinline__ void maxpool_body(char* smem, int bid,
                                             const float* __restrict__ P,
                                             const float* __restrict__ Q,
                                             const float* __restrict__ w2,
                                             float* __restrict__ out) {
  MaxpoolS& S = *(MaxpoolS*)smem;
  int lg = bid % 10;
  int bd = bid / 10;
  int b = bd >> 1, dir = bd & 1;
  int l0 = lg * 2;
  int t = threadIdx.x;
  int pi = t >> 4, qi = t & 15;
  float (*cosT0)[S_ + 1] = (float (*)[S_ + 1])&S.xp[0][0];
  float (*cosT1)[S_ + 1] = (float (*)[S_ + 1])&S.xq[0][0];
  const float* w2g = w2 + (size_t)(2 + dir) * L_ * H_ + (size_t)l0 * H_;
  for (int idx = t; idx < 2 * H_; idx += 256) S.w2s[idx / H_][idx % H_] = w2g[idx];
  float dot[2][16];
#pragma unroll
  for (int l = 0; l < 2; ++l)
#pragma unroll
    for (int k = 0; k < 16; ++k) dot[l][k] = 0.f;
  float np2[2] = {0.f, 0.f}, nq2[2] = {0.f, 0.f};
  const float* Pb = P + (size_t)b * S_ * H2_ + dir * H_;
  const float* Qb = Q + (size_t)b * S_ * H2_ + dir * H_;
  for (int c0 = 0; c0 < H_; c0 += 75) {
    __syncthreads();
    for (int idx = t; idx < S_ * 75; idx += 256) {
      int s = idx / 75, hh = idx - s * 75;
      S.xp[s][hh] = Pb[(size_t)s * H2_ + c0 + hh];
      S.xq[s][hh] = Qb[(size_t)s * H2_ + c0 + hh];
    }
    __syncthreads();
    for (int hh = 0; hh < 75; ++hh) {
      float w0 = S.w2s[0][c0 + hh], w1 = S.w2s[1][c0 + hh];
      float pv[4], qv[4];
#pragma unroll
      for (int i = 0; i < 4; ++i) pv[i] = S.xp[pi + 16 * i][hh];
#pragma unroll
      for (int j = 0; j < 4; ++j) qv[j] = S.xq[qi + 16 * j][hh];
      float p0[4], p1[4];
#pragma unroll
      for (int i = 0; i < 4; ++i) { p0[i] = pv[i] * w0; p1[i] = pv[i] * w1; }
#pragma unroll
      for (int i = 0; i < 4; ++i)
#pragma unroll
        for (int j = 0; j < 4; ++j) {
          dot[0][i * 4 + j] = fmaf(p0[i], qv[j], dot[0][i * 4 + j]);
          dot[1][i * 4 + j] = fmaf(p1[i], qv[j], dot[1][i * 4 + j]);
        }
    }
    if (t < S_) {
      for (int hh = 0; hh < 75; ++hh) {
        float v = S.xp[t][hh], vv = v * v;
        np2[0] = fmaf(S.w2s[0][c0 + hh], vv, np2[0]);
        np2[1] = fmaf(S.w2s[1][c0 + hh], vv, np2[1]);
      }
    } else if (t < 2 * S_) {
      int s2 = t - S_;
      for (int hh = 0; hh < 75; ++hh) {
        float v = S.xq[s2][hh], vv = v * v;
        nq2[0] = fmaf(S.w2s[0][c0 + hh], vv, nq2[0]);
        nq2[1] = fmaf(S.w2s[1][c0 + hh], vv, nq2[1]);
      }
    }
  }
  if (t < S_) { S.pn[0][t] = sqrtf(np2[0]); S.pn[1][t] = sqrtf(np2[1]); }
  else if (t < 2 * S_) { S.qn[0][t - S_] = sqrtf(nq2[0]); S.qn[1][t - S_] = sqrtf(nq2[1]); }
  __syncthreads();
#pragma unroll
  for (int i = 0; i < 4; ++i) {
    int p = pi + 16 * i;
#pragma unroll
    for (int j = 0; j < 4; ++j) {
      int q = qi + 16 * j;
      cosT0[p][q] = dot[0][i * 4 + j] / (S.pn[0][p] * S.qn[0][q]);
      cosT1[p][q] = dot[1][i * 4 + j] / (S.pn[1][p] * S.qn[1][q]);
    }
  }
  __syncthreads();
  if (t < S_) {
    float m0 = NEG_INF, m1 = NEG_INF;
    for (int q = 0; q < S_; ++q) { m0 = fmaxf(m0, cosT0[t][q]); m1 = fmaxf(m1, cosT1[t][q]); }
    size_t base = ((size_t)b * S_ + t) * ROW_ + (2 + dir) * L_ + l0;
    out[base] = m0; out[base + 1] = m1;
  } else if (t < 2 * S_) {
    int s2 = t - S_;
    float m0 = NEG_INF, m1 = NEG_INF;
    for (int p = 0; p < S_; ++p) { m0 = fmaxf(m0, cosT0[p][s2]); m1 = fmaxf(m1, cosT1[p][s2]); }
    size_t base = OUTQ_OFF + ((size_t)b * S_ + s2) * ROW_ + (2 + dir) * L_ + l0;
    out[base] = m0; out[base + 1] = m1;
  }
}

__device__ __forceinline__ void outs_body(char* smem, int bid,
                                          const float* __restrict__ P,
                                          const float* __restrict__ Q,
                                          const float* __restrict__ w2t,
                                          const float* __restrict__ cosM,
                                          const float* __restrict__ sum_p,
                                          const float* __restrict__ sum_q,
                                          float* __restrict__ out) {
  OutsS& S = *(OutsS*)smem;
  int bd = bid >> 4;
  int sg = bid & 15;
  int s0 = sg * SG;
  int b = bd >> 1, dir = bd & 1;
  int t = threadIdx.x;
  const float* cm = cosM + (size_t)bd * S_ * S_;
  for (int idx = t; idx < SG * S_; idx += 256) {
    int si = idx >> 6, k = idx & 63;
    S.cosC[si][k] = cm[k * S_ + s0 + si];
    S.cosR[si][k] = cm[(s0 + si) * S_ + k];
  }
  if (t < SG) { S.sps[t] = sum_p[bd * S_ + s0 + t]; S.sqs[t] = sum_q[bd * S_ + s0 + t]; }
  int tgt = dir ? 0 : S_ - 1;
  const float* Pb = P + (size_t)b * S_ * H2_ + dir * H_;
  const float* Qb = Q + (size_t)b * S_ * H2_ + dir * H_;
  for (int h = t; h < H_; h += 256) { S.tq[h] = Qb[(size_t)tgt * H2_ + h]; S.tp[h] = Pb[(size_t)tgt * H2_ + h]; }
  for (int idx = t; idx < SG * H_; idx += 256) {
    int si = idx / H_, h = idx - si * H_;
    S.xP[si][h] = Pb[(size_t)(s0 + si) * H2_ + h];
    S.xQ[si][h] = Qb[(size_t)(s0 + si) * H2_ + h];
  }
  __syncthreads();
  for (int h = t; h < H_; h += 256) {
    float amp[SG], amq[SG], axp[SG], axq[SG];
#pragma unroll
    for (int si = 0; si < SG; ++si) { amp[si] = 0.f; amq[si] = 0.f; axp[si] = NEG_INF; axq[si] = NEG_INF; }
    for (int k = 0; k < S_; k += 2) {
      float pv0 = Pb[(size_t)k * H2_ + h];
      float qv0 = Qb[(size_t)k * H2_ + h];
      float pv1 = Pb[(size_t)(k + 1) * H2_ + h];
      float qv1 = Qb[(size_t)(k + 1) * H2_ + h];
#pragma unroll
      for (int si = 0; si < SG; ++si) {
        float t1 = pv0 * S.cosC[si][k];
        amp[si] += t1; axp[si] = fmaxf(axp[si], t1);
        float t2 = qv0 * S.cosR[si][k];
        amq[si] += t2; axq[si] = fmaxf(axq[si], t2);
        float t3 = pv1 * S.cosC[si][k + 1];
        amp[si] += t3; axp[si] = fmaxf(axp[si], t3);
        float t4 = qv1 * S.cosR[si][k + 1];
        amq[si] += t4; axq[si] = fmaxf(axq[si], t4);
      }
    }
#pragma unroll
    for (int si = 0; si < SG; ++si) {
      S.vmq[si][h] = amq[si] / S.sqs[si];
      S.vmp[si][h] = amp[si] / S.sps[si];
      S.vxq[si][h] = axq[si];
      S.vxp[si][h] = axp[si];
    }
  }
  __syncthreads();
  if (t < 240) {
    const int wb_[6] = {0, 0, 4, 4, 6, 6};
#pragma unroll
    for (int r = 0; r < 2; ++r) {
      int job = t + 240 * r;
      int l = job % L_;
      int g = job / L_;
      int pr = g % 6, si = g / 6;
      const float* x = (pr & 1) ? S.xQ[si] : S.xP[si];
      const float* y;
      if (pr == 0) y = S.tq;
      else if (pr == 1) y = S.tp;
      else if (pr == 2) y = S.vmq[si];
      else if (pr == 3) y = S.vmp[si];
      else if (pr == 4) y = S.vxq[si];
      else y = S.vxp[si];
      int widx = wb_[pr] + dir;
      const float* wp = w2t + (size_t)widx * (L_ * H_) + l;
      float a1 = 0.f, a2 = 0.f, a3 = 0.f;
      for (int h = 0; h < H_; ++h) {
        float wv = wp[h * L_];
        float xx = x[h], yy = y[h];
        float wx = wv * xx;
        a1 = fmaf(wx, yy, a1);
        a2 = fmaf(wx, xx, a2);
        a3 = fmaf(wv * yy, yy, a3);
      }
      float den = fmaxf(sqrtf(a2) * sqrtf(a3), 1e-8f);   // EPS per _mp_cos
      float c = a1 / den;
      int s = s0 + si;
      size_t base = ((pr & 1) ? OUTQ_OFF : 0) + ((size_t)b * S_ + s) * ROW_;
      out[base + (size_t)widx * L_ + l] = c;
    }
  }
}

__global__ __launch_bounds__(256) void k_main(const float* __restrict__ P,
                                              const float* __restrict__ Q,
                                              const float* __restrict__ w2,
                                              const float* __restrict__ w2t,
                                              const float* __restrict__ cosM,
                                              const float* __restrict__ sum_p,
                                              const float* __restrict__ sum_q,
                                              float* __restrict__ out) {
  extern __shared__ char smem[];
  int bid = blockIdx.x;
  if (bid < B_ * 2 * 10) maxpool_body(smem, bid, P, Q, w2, out);
  else outs_body(smem, bid - B_ * 2 * 10, P, Q, w2t, cosM, sum_p, sum_q, out);
}

extern "C" void kernel_launch(void* const* d_in, const int* in_sizes, int n_in,
                              void* d_out, int out_size, void* d_ws, size_t ws_size,
                              hipStream_t stream) {
  (void)out_size; (void)ws_size;
  int iw = 2;
  for (int i = 0; i < n_in; ++i) if (in_sizes[i] == 8 * L_ * H_) iw = i;
  int io[2] = {0, 1}, k = 0;
  for (int i = 0; i < n_in && k < 2; ++i) if (i != iw) io[k++] = i;
  const float* P  = (const float*)d_in[io[0]];
  const float* Q  = (const float*)d_in[io[1]];
  const float* Wf = (const float*)d_in[iw];
  float* out = (float*)d_out;

  float* ws = (float*)d_ws;         // ~1.46 MB
  float* w2    = ws;                // 48000
  float* w2t   = w2 + 48000;        // 48000
  float* cosM  = w2t + 48000;       // 262144
  float* sum_p = cosM + 262144;     // 4096 (zeroed by k_w2, atomic target)
  float* sum_q = sum_p + 4096;      // 4096

  size_t shbytes = sizeof(MaxpoolS) > sizeof(OutsS) ? sizeof(MaxpoolS) : sizeof(OutsS);
  k_w2<<<(8 * L_ * H_ + 255) / 256, 256, 0, stream>>>(Wf, w2, w2t, sum_p);
  k_cos<<<dim3(B_ * 2, 4), 256, 0, stream>>>(P, Q, cosM, sum_p, sum_q);
  k_main<<<B_ * 2 * 10 + B_ * 2 * 16, 256, shbytes, stream>>>(P, Q, w2, w2t, cosM, sum_p, sum_q, out);
}

// Round 11
// 208.627 us; speedup vs baseline: 1.3276x; 1.0615x over previous
//
#include <hip/hip_runtime.h>
#include <hip/hip_bf16.h>

#define B_ 32
#define S_ 64
#define H_ 300
#define H2_ 600
#define L_ 20
#define ROW_ 160                    // 8 pieces * 20
#define OUTQ_OFF ((size_t)B_ * S_ * ROW_)
#define NEG_INF -3.402823466e38f

// ---------------- K0: w^2 tables + zero sum_p (atomic target in k_cos)
__global__ void k_w2(const float* __restrict__ Wf, float* __restrict__ w2,
                     float* __restrict__ w2t, float* __restrict__ sum_p) {
  int i = blockIdx.x * 256 + threadIdx.x;
  if (i < 8 * L_ * H_) {
    float v = Wf[i];
    float v2 = v * v;
    w2[i] = v2;
    int widx = i / (L_ * H_);
    int r = i - widx * (L_ * H_);
    int l = r / H_;
    int h = r - l * H_;
    w2t[widx * (L_ * H_) + h * L_ + l] = v2;
  }
  if (i < B_ * 2 * S_) sum_p[i] = 0.f;
}

// ---------------- K1: cosine matrix, block = (bd, 16-row p-group) (r10: pass)
__global__ __launch_bounds__(256) void k_cos(const float* __restrict__ P,
                                             const float* __restrict__ Q,
                                             float* __restrict__ cosM,
                                             float* __restrict__ sum_p,
                                             float* __restrict__ sum_q) {
  int bd = blockIdx.x;
  int pg = blockIdx.y;
  int p0 = pg * 16;
  int b = bd >> 1, dir = bd & 1;
  __shared__ float xp[16][101];
  __shared__ float xq[S_][101];
  __shared__ float pn[16], qn[S_];
  __shared__ float cosL[16][S_ + 1];
  int t = threadIdx.x;
  int q = t & 63, pr = t >> 6;
  float dot[4] = {0.f, 0.f, 0.f, 0.f};
  float np2 = 0.f, nq2 = 0.f;
  const float* Pb = P + (size_t)b * S_ * H2_ + dir * H_;
  const float* Qb = Q + (size_t)b * S_ * H2_ + dir * H_;
  for (int c0 = 0; c0 < H_; c0 += 100) {
    __syncthreads();
    for (int idx = t; idx < 16 * 100; idx += 256) {
      int s = idx / 100, hh = idx - s * 100;
      xp[s][hh] = Pb[(size_t)(p0 + s) * H2_ + c0 + hh];
    }
    for (int idx = t; idx < S_ * 100; idx += 256) {
      int s = idx / 100, hh = idx - s * 100;
      xq[s][hh] = Qb[(size_t)s * H2_ + c0 + hh];
    }
    __syncthreads();
    for (int hh = 0; hh < 100; ++hh) {
      float qv = xq[q][hh];
#pragma unroll
      for (int i = 0; i < 4; ++i) dot[i] = fmaf(xp[pr + 4 * i][hh], qv, dot[i]);
    }
    if (t < 16) {
      for (int hh = 0; hh < 100; ++hh) { float v = xp[t][hh]; np2 = fmaf(v, v, np2); }
    } else if (t >= 64 && t < 128) {
      int s2 = t - 64;
      for (int hh = 0; hh < 100; ++hh) { float v = xq[s2][hh]; nq2 = fmaf(v, v, nq2); }
    }
  }
  if (t < 16) pn[t] = sqrtf(np2);
  else if (t >= 64 && t < 128) qn[t - 64] = sqrtf(nq2);
  __syncthreads();
  float* cm = cosM + (size_t)bd * S_ * S_;
#pragma unroll
  for (int i = 0; i < 4; ++i) {
    int p = pr + 4 * i;
    float c = dot[i] / (pn[p] * qn[q]);
    cosL[p][q] = c;
    cm[(size_t)(p0 + p) * S_ + q] = c;
  }
  __syncthreads();
  if (t < 16) {
    double acc = 0.0;
    for (int qq = 0; qq < S_; ++qq) acc += (double)cosL[t][qq];
    sum_q[bd * S_ + p0 + t] = (float)acc;
  } else if (t >= 64 && t < 128) {
    int qq = t - 64;
    float acc = 0.f;
    for (int p = 0; p < 16; ++p) acc += cosL[p][qq];
    atomicAdd(&sum_p[bd * S_ + qq], acc);
  }
}

// ======== fused main kernel ========
// R11: maxpool chunk 75 -> 65: MaxpoolS 41.8 -> 36.7 KB, max(36.7,33.3)*4 =
// 147 KB <= 160 KB -> 4 blocks/CU (was 3). cosT alias 2*64*65*4 = 33.28 KB
// fits xp+xq exactly.
#define CW 65
struct MaxpoolS {              // 36704 B
  float xp[S_][CW];
  float xq[S_][CW];
  float w2s[2][H_];
  float pn[2][S_], qn[2][S_];
};
#define SG 4
struct OutsS {                 // 33312 B
  float cosC[SG][S_];
  float cosR[SG][S_];
  float tq[H_], tp[H_];
  float xP[SG][H_], xQ[SG][H_];
  float vmq[SG][H_], vmp[SG][H_], vxq[SG][H_], vxp[SG][H_];
  float sps[SG], sqs[SG];
};

__device__ __forceinline__ void maxpool_body(char* smem, int bid,
                                             const float* __restrict__ P,
                                             const float* __restrict__ Q,
                                             const float* __restrict__ w2,
                                             float* __restrict__ out) {
  MaxpoolS& S = *(MaxpoolS*)smem;
  int lg = bid % 10;
  int bd = bid / 10;
  int b = bd >> 1, dir = bd & 1;
  int l0 = lg * 2;
  int t = threadIdx.x;
  int pi = t >> 4, qi = t & 15;
  float (*cosT0)[CW] = (float (*)[CW])&S.xp[0][0];   // 64*65 floats, exact fit
  float (*cosT1)[CW] = (float (*)[CW])&S.xq[0][0];
  const float* w2g = w2 + (size_t)(2 + dir) * L_ * H_ + (size_t)l0 * H_;
  for (int idx = t; idx < 2 * H_; idx += 256) S.w2s[idx / H_][idx % H_] = w2g[idx];
  float dot[2][16];
#pragma unroll
  for (int l = 0; l < 2; ++l)
#pragma unroll
    for (int k = 0; k < 16; ++k) dot[l][k] = 0.f;
  float np2[2] = {0.f, 0.f}, nq2[2] = {0.f, 0.f};
  const float* Pb = P + (size_t)b * S_ * H2_ + dir * H_;
  const float* Qb = Q + (size_t)b * S_ * H2_ + dir * H_;
  for (int c0 = 0; c0 < H_; c0 += CW) {
    int cw = (H_ - c0 < CW) ? (H_ - c0) : CW;
    __syncthreads();
    for (int idx = t; idx < S_ * CW; idx += 256) {
      int s = idx / CW, hh = idx - s * CW;
      if (hh < cw) {
        S.xp[s][hh] = Pb[(size_t)s * H2_ + c0 + hh];
        S.xq[s][hh] = Qb[(size_t)s * H2_ + c0 + hh];
      }
    }
    __syncthreads();
    for (int hh = 0; hh < cw; ++hh) {
      float w0 = S.w2s[0][c0 + hh], w1 = S.w2s[1][c0 + hh];
      float pv[4], qv[4];
#pragma unroll
      for (int i = 0; i < 4; ++i) pv[i] = S.xp[pi + 16 * i][hh];
#pragma unroll
      for (int j = 0; j < 4; ++j) qv[j] = S.xq[qi + 16 * j][hh];
      float p0[4], p1[4];
#pragma unroll
      for (int i = 0; i < 4; ++i) { p0[i] = pv[i] * w0; p1[i] = pv[i] * w1; }
#pragma unroll
      for (int i = 0; i < 4; ++i)
#pragma unroll
        for (int j = 0; j < 4; ++j) {
          dot[0][i * 4 + j] = fmaf(p0[i], qv[j], dot[0][i * 4 + j]);
          dot[1][i * 4 + j] = fmaf(p1[i], qv[j], dot[1][i * 4 + j]);
        }
    }
    if (t < S_) {
      for (int hh = 0; hh < cw; ++hh) {
        float v = S.xp[t][hh], vv = v * v;
        np2[0] = fmaf(S.w2s[0][c0 + hh], vv, np2[0]);
        np2[1] = fmaf(S.w2s[1][c0 + hh], vv, np2[1]);
      }
    } else if (t < 2 * S_) {
      int s2 = t - S_;
      for (int hh = 0; hh < cw; ++hh) {
        float v = S.xq[s2][hh], vv = v * v;
        nq2[0] = fmaf(S.w2s[0][c0 + hh], vv, nq2[0]);
        nq2[1] = fmaf(S.w2s[1][c0 + hh], vv, nq2[1]);
      }
    }
  }
  if (t < S_) { S.pn[0][t] = sqrtf(np2[0]); S.pn[1][t] = sqrtf(np2[1]); }
  else if (t < 2 * S_) { S.qn[0][t - S_] = sqrtf(nq2[0]); S.qn[1][t - S_] = sqrtf(nq2[1]); }
  __syncthreads();
#pragma unroll
  for (int i = 0; i < 4; ++i) {
    int p = pi + 16 * i;
#pragma unroll
    for (int j = 0; j < 4; ++j) {
      int q = qi + 16 * j;
      cosT0[p][q] = dot[0][i * 4 + j] / (S.pn[0][p] * S.qn[0][q]);
      cosT1[p][q] = dot[1][i * 4 + j] / (S.pn[1][p] * S.qn[1][q]);
    }
  }
  __syncthreads();
  if (t < S_) {
    float m0 = NEG_INF, m1 = NEG_INF;
    for (int q = 0; q < S_; ++q) { m0 = fmaxf(m0, cosT0[t][q]); m1 = fmaxf(m1, cosT1[t][q]); }
    size_t base = ((size_t)b * S_ + t) * ROW_ + (2 + dir) * L_ + l0;
    out[base] = m0; out[base + 1] = m1;
  } else if (t < 2 * S_) {
    int s2 = t - S_;
    float m0 = NEG_INF, m1 = NEG_INF;
    for (int p = 0; p < S_; ++p) { m0 = fmaxf(m0, cosT0[p][s2]); m1 = fmaxf(m1, cosT1[p][s2]); }
    size_t base = OUTQ_OFF + ((size_t)b * S_ + s2) * ROW_ + (2 + dir) * L_ + l0;
    out[base] = m0; out[base + 1] = m1;
  }
}

__device__ __forceinline__ void outs_body(char* smem, int bid,
                                          const float* __restrict__ P,
                                          const float* __restrict__ Q,
                                          const float* __restrict__ w2t,
                                          const float* __restrict__ cosM,
                                          const float* __restrict__ sum_p,
                                          const float* __restrict__ sum_q,
                                          float* __restrict__ out) {
  OutsS& S = *(OutsS*)smem;
  int bd = bid >> 4;
  int sg = bid & 15;
  int s0 = sg * SG;
  int b = bd >> 1, dir = bd & 1;
  int t = threadIdx.x;
  const float* cm = cosM + (size_t)bd * S_ * S_;
  for (int idx = t; idx < SG * S_; idx += 256) {
    int si = idx >> 6, k = idx & 63;
    S.cosC[si][k] = cm[k * S_ + s0 + si];
    S.cosR[si][k] = cm[(s0 + si) * S_ + k];
  }
  if (t < SG) { S.sps[t] = sum_p[bd * S_ + s0 + t]; S.sqs[t] = sum_q[bd * S_ + s0 + t]; }
  int tgt = dir ? 0 : S_ - 1;
  const float* Pb = P + (size_t)b * S_ * H2_ + dir * H_;
  const float* Qb = Q + (size_t)b * S_ * H2_ + dir * H_;
  for (int h = t; h < H_; h += 256) { S.tq[h] = Qb[(size_t)tgt * H2_ + h]; S.tp[h] = Pb[(size_t)tgt * H2_ + h]; }
  for (int idx = t; idx < SG * H_; idx += 256) {
    int si = idx / H_, h = idx - si * H_;
    S.xP[si][h] = Pb[(size_t)(s0 + si) * H2_ + h];
    S.xQ[si][h] = Qb[(size_t)(s0 + si) * H2_ + h];
  }
  __syncthreads();
  for (int h = t; h < H_; h += 256) {
    float amp[SG], amq[SG], axp[SG], axq[SG];
#pragma unroll
    for (int si = 0; si < SG; ++si) { amp[si] = 0.f; amq[si] = 0.f; axp[si] = NEG_INF; axq[si] = NEG_INF; }
    for (int k = 0; k < S_; k += 2) {
      float pv0 = Pb[(size_t)k * H2_ + h];
      float qv0 = Qb[(size_t)k * H2_ + h];
      float pv1 = Pb[(size_t)(k + 1) * H2_ + h];
      float qv1 = Qb[(size_t)(k + 1) * H2_ + h];
#pragma unroll
      for (int si = 0; si < SG; ++si) {
        float t1 = pv0 * S.cosC[si][k];
        amp[si] += t1; axp[si] = fmaxf(axp[si], t1);
        float t2 = qv0 * S.cosR[si][k];
        amq[si] += t2; axq[si] = fmaxf(axq[si], t2);
        float t3 = pv1 * S.cosC[si][k + 1];
        amp[si] += t3; axp[si] = fmaxf(axp[si], t3);
        float t4 = qv1 * S.cosR[si][k + 1];
        amq[si] += t4; axq[si] = fmaxf(axq[si], t4);
      }
    }
#pragma unroll
    for (int si = 0; si < SG; ++si) {
      S.vmq[si][h] = amq[si] / S.sqs[si];
      S.vmp[si][h] = amp[si] / S.sps[si];
      S.vxq[si][h] = axq[si];
      S.vxp[si][h] = axp[si];
    }
  }
  __syncthreads();
  if (t < 240) {
    const int wb_[6] = {0, 0, 4, 4, 6, 6};
#pragma unroll
    for (int r = 0; r < 2; ++r) {
      int job = t + 240 * r;
      int l = job % L_;
      int g = job / L_;
      int pr = g % 6, si = g / 6;
      const float* x = (pr & 1) ? S.xQ[si] : S.xP[si];
      const float* y;
      if (pr == 0) y = S.tq;
      else if (pr == 1) y = S.tp;
      else if (pr == 2) y = S.vmq[si];
      else if (pr == 3) y = S.vmp[si];
      else if (pr == 4) y = S.vxq[si];
      else y = S.vxp[si];
      int widx = wb_[pr] + dir;
      const float* wp = w2t + (size_t)widx * (L_ * H_) + l;
      float a1 = 0.f, a2 = 0.f, a3 = 0.f;
      for (int h = 0; h < H_; ++h) {
        float wv = wp[h * L_];
        float xx = x[h], yy = y[h];
        float wx = wv * xx;
        a1 = fmaf(wx, yy, a1);
        a2 = fmaf(wx, xx, a2);
        a3 = fmaf(wv * yy, yy, a3);
      }
      float den = fmaxf(sqrtf(a2) * sqrtf(a3), 1e-8f);   // EPS per _mp_cos
      float c = a1 / den;
      int s = s0 + si;
      size_t base = ((pr & 1) ? OUTQ_OFF : 0) + ((size_t)b * S_ + s) * ROW_;
      out[base + (size_t)widx * L_ + l] = c;
    }
  }
}

__global__ __launch_bounds__(256) void k_main(const float* __restrict__ P,
                                              const float* __restrict__ Q,
                                              const float* __restrict__ w2,
                                              const float* __restrict__ w2t,
                                              const float* __restrict__ cosM,
                                              const float* __restrict__ sum_p,
                                              const float* __restrict__ sum_q,
                                              float* __restrict__ out) {
  extern __shared__ char smem[];
  int bid = blockIdx.x;
  if (bid < B_ * 2 * 10) maxpool_body(smem, bid, P, Q, w2, out);
  else outs_body(smem, bid - B_ * 2 * 10, P, Q, w2t, cosM, sum_p, sum_q, out);
}

extern "C" void kernel_launch(void* const* d_in, const int* in_sizes, int n_in,
                              void* d_out, int out_size, void* d_ws, size_t ws_size,
                              hipStream_t stream) {
  (void)out_size; (void)ws_size;
  int iw = 2;
  for (int i = 0; i < n_in; ++i) if (in_sizes[i] == 8 * L_ * H_) iw = i;
  int io[2] = {0, 1}, k = 0;
  for (int i = 0; i < n_in && k < 2; ++i) if (i != iw) io[k++] = i;
  const float* P  = (const float*)d_in[io[0]];
  const float* Q  = (const float*)d_in[io[1]];
  const float* Wf = (const float*)d_in[iw];
  float* out = (float*)d_out;

  float* ws = (float*)d_ws;         // ~1.46 MB
  float* w2    = ws;                // 48000
  float* w2t   = w2 + 48000;        // 48000
  float* cosM  = w2t + 48000;       // 262144
  float* sum_p = cosM + 262144;     // 4096 (zeroed by k_w2, atomic target)
  float* sum_q = sum_p + 4096;      // 4096

  size_t shbytes = sizeof(MaxpoolS) > sizeof(OutsS) ? sizeof(MaxpoolS) : sizeof(OutsS);
  k_w2<<<(8 * L_ * H_ + 255) / 256, 256, 0, stream>>>(Wf, w2, w2t, sum_p);
  k_cos<<<dim3(B_ * 2, 4), 256, 0, stream>>>(P, Q, cosM, sum_p, sum_q);
  k_main<<<B_ * 2 * 10 + B_ * 2 * 16, 256, shbytes, stream>>>(P, Q, w2, w2t, cosM, sum_p, sum_q, out);
}